// Round 8
// baseline (135.886 us; speedup 1.0000x reference)
//
#include <hip/hip_runtime.h>

typedef unsigned short u16;
typedef unsigned int u32;
typedef __attribute__((ext_vector_type(8))) __bf16 bf16x8;
typedef __attribute__((ext_vector_type(4))) float f32x4;
typedef __attribute__((ext_vector_type(16))) float f32x16;
typedef __attribute__((ext_vector_type(4))) u32 u32x4;

#define LOG2E 1.44269504088896340736f

__device__ __forceinline__ u16 f2bf(float f) {
  u32 u = __builtin_bit_cast(u32, f);
  u += 0x7fffu + ((u >> 16) & 1u);
  return (u16)(u >> 16);
}

__device__ __forceinline__ void async_copy16(const u16* g, u16* l) {
  __builtin_amdgcn_global_load_lds((const __attribute__((address_space(1))) void*)g,
                                   (__attribute__((address_space(3))) void*)l,
                                   16, 0, 0);
}

__device__ __forceinline__ bf16x8 ldb8(const u16* p) {
  return *(const bf16x8*)p;
}

// ---------------------------------------------------------------------------
// Kernel 1: fused f32 -> bf16 conversion of [query, key, value, Wq, Wk, Wv, Wo]
// into one contiguous bf16 region (16M elements).
// ---------------------------------------------------------------------------
__global__ __launch_bounds__(256) void convert_kernel(
    const float* __restrict__ q, const float* __restrict__ k, const float* __restrict__ v,
    const float* __restrict__ wq, const float* __restrict__ wk,
    const float* __restrict__ wv, const float* __restrict__ wo,
    u16* __restrict__ out)
{
  size_t t = (size_t)blockIdx.x * 256 + threadIdx.x;  // 0 .. 2M-1
  size_t e = t * 8;
  const float* src;
  size_t off;
  if (e < 12582912) {            // 3 x 4M qkv region
    int which = (int)(e >> 22);
    src = (which == 0) ? q : ((which == 1) ? k : v);
    off = e & 4194303;
  } else {                        // 4 x 1M weight region
    size_t r = e - 12582912;
    int which = (int)(r >> 20);
    src = (which == 0) ? wq : ((which == 1) ? wk : ((which == 2) ? wv : wo));
    off = r & 1048575;
  }
  float4 f0 = *(const float4*)(src + off);
  float4 f1 = *(const float4*)(src + off + 4);
  ushort4 u0, u1;
  u0.x = f2bf(f0.x); u0.y = f2bf(f0.y); u0.z = f2bf(f0.z); u0.w = f2bf(f0.w);
  u1.x = f2bf(f1.x); u1.y = f2bf(f1.y); u1.z = f2bf(f1.z); u1.w = f2bf(f1.w);
  *(ushort4*)(out + e) = u0;
  *(ushort4*)(out + e + 4) = u1;
}

// ---------------------------------------------------------------------------
// bf16 GEMM core: C[M=4096, N=1024] = A[M,1024] @ W[N,1024]^T + bias
// 128x128 tile, BK=32, 4 waves (2x2), 16x16x32 MFMA.
// R7: 3-buffer depth-2 pipeline, 48 KB LDS -> 3 blocks/CU (full residency of
// the 768-block grid). STAGE(t+2) is issued AFTER barrier t: once barrier t
// releases, no wave can still be reading buf[(t-1)%3], so writing
// buf[(t+2)%3] == buf[(t-1)%3] is race-free with only 3 buffers.
// Counted s_waitcnt vmcnt(4): drains own stage-t loads (issued ~2 iters ago)
// while stage t+1 stays in flight. s_setprio(1) around the MFMA cluster (T5).
// Bank swizzle (measured 0-conflict in R6): chunk cc of row stored at slot
// cc^((row>>1)&3), pre-swizzled global source + same XOR on ds_read.
// MODE 0: bf16 out, permuted [b,h,s,64], value scaled by `scale`
// MODE 1: bf16 out, transposed [b,h,64,s]  (for V)
// MODE 2: f32 out, plain row-major [M,N]
// ---------------------------------------------------------------------------
template <int MODE>
__device__ __forceinline__ void gemm128(
    const u16* __restrict__ A, const u16* __restrict__ W,
    const float* __restrict__ bias, void* __restrict__ out,
    float scale, u16* As, u16* Bs)
{
  const int tid = threadIdx.x;
  const int wid = tid >> 6, lane = tid & 63;
  const int g = lane >> 4, l16 = lane & 15;
  const int wr = wid >> 1, wc = wid & 1;
  const int brow = blockIdx.x * 128, bcol = blockIdx.y * 128;

  f32x4 acc[4][4] = {};
  const u16* Ab = A + (size_t)brow * 1024;
  const u16* Wb = W + (size_t)bcol * 1024;

  // stage K-tile kt2 into buffer `buf`: 4 global_load_lds per thread.
  auto STAGE = [&](int buf, int kt2) {
    const int k0 = kt2 * 32;
    u16* Ad = As + buf * 4096;
    u16* Bd = Bs + buf * 4096;
#pragma unroll
    for (int i = 0; i < 2; ++i) {
      const int chunk = i * 256 + wid * 64 + lane;
      const int row = chunk >> 2, cc = chunk & 3;
      const int sc = (cc ^ ((row >> 1) & 3)) * 8;   // pre-swizzled source chunk
      const size_t goff = (size_t)row * 1024 + k0 + sc;
      const int lbase = (i * 256 + wid * 64) * 8;   // elements; HW adds lane*16B
      async_copy16(Ab + goff, Ad + lbase);
      async_copy16(Wb + goff, Bd + lbase);
    }
  };

  STAGE(0, 0);
  STAGE(1, 1);
  int rd = 0, wr2 = 2;

  for (int kt = 0; kt < 32; ++kt) {
    if (kt < 31) {
      asm volatile("s_waitcnt vmcnt(4)" ::: "memory");  // own stage-kt done
    } else {
      asm volatile("s_waitcnt vmcnt(0)" ::: "memory");
    }
    __builtin_amdgcn_s_barrier();
    asm volatile("" ::: "memory");  // pin ds_reads below the barrier
    if (kt < 30) {
      STAGE(wr2, kt + 2);
      wr2 = (wr2 == 2) ? 0 : wr2 + 1;
    }

    const u16* Ac = As + rd * 4096;
    const u16* Bc = Bs + rd * 4096;
    rd = (rd == 2) ? 0 : rd + 1;

    bf16x8 a[4], b[4];
#pragma unroll
    for (int m = 0; m < 4; ++m) {
      const int row = wr * 64 + m * 16 + l16;
      a[m] = ldb8(Ac + row * 32 + ((g ^ ((row >> 1) & 3)) * 8));
    }
#pragma unroll
    for (int n = 0; n < 4; ++n) {
      const int row = wc * 64 + n * 16 + l16;
      b[n] = ldb8(Bc + row * 32 + ((g ^ ((row >> 1) & 3)) * 8));
    }
    __builtin_amdgcn_s_setprio(1);
#pragma unroll
    for (int m = 0; m < 4; ++m)
#pragma unroll
      for (int n = 0; n < 4; ++n)
        acc[m][n] = __builtin_amdgcn_mfma_f32_16x16x32_bf16(a[m], b[n], acc[m][n], 0, 0, 0);
    __builtin_amdgcn_s_setprio(0);
  }

  // epilogue
#pragma unroll
  for (int m = 0; m < 4; ++m) {
    const int mg = brow + wr * 64 + m * 16 + g * 4;  // + j
#pragma unroll
    for (int n = 0; n < 4; ++n) {
      const int cg = bcol + wc * 64 + n * 16 + l16;
      const float bb = bias[cg];
      if constexpr (MODE == 0) {
        const int h = cg >> 6, d = cg & 63;
#pragma unroll
        for (int j = 0; j < 4; ++j) {
          const int row = mg + j;
          const int bb_ = row >> 11, s = row & 2047;
          ((u16*)out)[(((size_t)(bb_ * 16 + h) * 2048 + s) << 6) + d] =
              f2bf((acc[m][n][j] + bb) * scale);
        }
      } else if constexpr (MODE == 1) {
        const int h = cg >> 6, d = cg & 63;
        const int bb_ = mg >> 11, s0 = mg & 2047;
        ushort4 pk;
        pk.x = f2bf(acc[m][n][0] + bb);
        pk.y = f2bf(acc[m][n][1] + bb);
        pk.z = f2bf(acc[m][n][2] + bb);
        pk.w = f2bf(acc[m][n][3] + bb);
        *(ushort4*)((u16*)out + ((size_t)(bb_ * 16 + h) * 64 + d) * 2048 + s0) = pk;
      } else {
#pragma unroll
        for (int j = 0; j < 4; ++j) {
          const int row = mg + j;
          ((float*)out)[(size_t)row * 1024 + cg] = acc[m][n][j] + bb;
        }
      }
    }
  }
}

__global__ __launch_bounds__(256) void qkv_gemm_kernel(
    const u16* __restrict__ xq, const u16* __restrict__ xk, const u16* __restrict__ xv,
    const u16* __restrict__ wq, const u16* __restrict__ wk, const u16* __restrict__ wv,
    const float* __restrict__ bq, const float* __restrict__ bk, const float* __restrict__ bv,
    u16* __restrict__ oq, u16* __restrict__ ok, u16* __restrict__ ov)
{
  __shared__ u16 As[3][4096];
  __shared__ u16 Bs[3][4096];
  const int z = blockIdx.z;
  // Q pre-scaled by 1/sqrt(64) * log2(e): attention then uses p = exp2(s) directly.
  if (z == 0)      gemm128<0>(xq, wq, bq, oq, 0.125f * LOG2E, &As[0][0], &Bs[0][0]);
  else if (z == 1) gemm128<0>(xk, wk, bk, ok, 1.0f, &As[0][0], &Bs[0][0]);    // K
  else             gemm128<1>(xv, wv, bv, ov, 1.0f, &As[0][0], &Bs[0][0]);    // V transposed
}

__global__ __launch_bounds__(256) void out_gemm_kernel(
    const u16* __restrict__ a, const u16* __restrict__ w,
    const float* __restrict__ bias, float* __restrict__ o)
{
  __shared__ u16 As[3][4096];
  __shared__ u16 Bs[3][4096];
  gemm128<2>(a, w, bias, o, 1.0f, &As[0][0], &Bs[0][0]);
}

// ---------------------------------------------------------------------------
// Kernel 3: flash attention, 32x32x16 MFMA, swapped QK^T (T12), in-register P
// via v_cvt_pk_bf16_f32 + 2 x v_permlane32_swap_b32 per k-step, fixed-max
// softmax, row-sum on the matrix pipe (ones-MFMA), s_setprio, depth-2
// prefetch with 4 LDS buffers and counted vmcnt.
// R7: K/V tiles re-laid-out as TWO 64-byte-row half-tiles [2][64][32] with the
// GEMM-proven zero-conflict swizzle (slot ^ ((row>>1)&3)) -- the old 128-byte
// rows cost 4 conflict-cycles per ds_read_b128 (4.2M/dispatch, ~11%).
// Grid 512 (XCD-chunked: each XCD owns 4 whole heads), 4 waves x 32 q-rows.
// ---------------------------------------------------------------------------
__global__ __launch_bounds__(256) void attn_kernel(
    const u16* __restrict__ qp, const u16* __restrict__ kp,
    const u16* __restrict__ vt, u16* __restrict__ ao)
{
  __shared__ u16 Kbuf[4][4096];      // [4][2 d-half][64 k][32] bf16, 8 KB each
  __shared__ u16 Vbuf[4][4096];      // [4][2 s-half][64 d][32] bf16, 8 KB each

  const int wid = threadIdx.x >> 6, lane = threadIdx.x & 63;
  const int u = lane >> 5, l32 = lane & 31;

  // XCD-chunked remap: 512 blocks, 8 XCDs -> each XCD owns 4 whole heads.
  int bid = (int)blockIdx.x;
  bid = (bid & 7) * 64 + (bid >> 3);
  const int bh = bid >> 4;                 // b*16 + h
  const int q0 = (bid & 15) * 128 + wid * 32;

  const u16* Q = qp + ((size_t)bh * 2048 + q0) * 64;
  const u16* K = kp + (size_t)bh * 2048 * 64;
  const u16* V = vt + (size_t)bh * 64 * 2048;

  // Q as B-fragments: col = q = l32, k-window = u*8 within each 16-d step
  bf16x8 aq[4];
#pragma unroll
  for (int st = 0; st < 4; ++st)
    aq[st] = ldb8(Q + l32 * 64 + st * 16 + u * 8);

  f32x16 outa[2] = {};   // C[q_row][d=nb*32+l32]
  f32x16 outsum = {};    // C[q_row][*] = running row-sum of P (denominator)
  f32x16 zf16 = {};

  const __bf16 one_bf = (__bf16)1.0f;
  bf16x8 ones = {one_bf, one_bf, one_bf, one_bf, one_bf, one_bf, one_bf, one_bf};

  // stage tile kb into buffer `buf`: 4 global_load_lds per thread (2 K + 2 V).
  // LDS layout [half][row][32] per matrix; chunk c = half*256 + row*4 + slot;
  // linear LDS dest, pre-swizzled global source slot sc = slot^((row>>1)&3).
  auto STAGE = [&](int buf, int kb) {
#pragma unroll
    for (int i = 0; i < 2; ++i) {
      const int c = i * 256 + wid * 64 + lane;   // i == half
      const int row = (c & 255) >> 2, slot = c & 3;
      const int sc = (slot ^ ((row >> 1) & 3)) * 8;
      const int lbase = (i * 256 + wid * 64) * 8;  // elements; HW adds lane*16B
      async_copy16(K + (size_t)(kb + row) * 64 + i * 32 + sc, &Kbuf[buf][lbase]);
      async_copy16(V + (size_t)row * 2048 + kb + i * 32 + sc, &Vbuf[buf][lbase]);
    }
  };

  STAGE(0, 0);
  STAGE(1, 64);

  for (int kt = 0; kt < 32; ++kt) {
    // T4: counted vmcnt -- wait only for stage kt (4 loads/thread/stage).
    if (kt < 30) {
      STAGE((kt + 2) & 3, (kt + 2) * 64);
      asm volatile("s_waitcnt vmcnt(8)" ::: "memory");
    } else if (kt == 30) {
      asm volatile("s_waitcnt vmcnt(4)" ::: "memory");
    } else {
      asm volatile("s_waitcnt vmcnt(0)" ::: "memory");
    }
    __builtin_amdgcn_s_barrier();
    asm volatile("" ::: "memory");  // pin ds_reads below the barrier

    const u16* Kb = Kbuf[kt & 3];
    const u16* Vb = Vbuf[kt & 3];

    // Swapped QK^T: s[half] = K[half*32..+31][:] . Q -> P[k][q=l32]
    // k = half*32 + (reg&3) + 8*(reg>>2) + 4u
    // K frag element st*16+u*8 -> d-half st>>1, slot (st&1)*2+u, row krow.
    f32x16 s[2];
    __builtin_amdgcn_s_setprio(1);
#pragma unroll
    for (int half = 0; half < 2; ++half) {
      const int krow = half * 32 + l32;
#pragma unroll
      for (int st = 0; st < 4; ++st) {
        const bf16x8 kf = ldb8(Kb + (st >> 1) * 2048 + krow * 32 +
                               ((((st & 1) * 2 + u) ^ ((krow >> 1) & 3)) * 8));
        s[half] = __builtin_amdgcn_mfma_f32_32x32x16_bf16(
            kf, aq[st], (st == 0) ? zf16 : s[half], 0, 0, 0);
      }
    }
    __builtin_amdgcn_s_setprio(0);

    // p = exp2(s); pack adjacent-k pairs to one bf16x2 word per cvt_pk inst
    u32 Wd[2][8];
#pragma unroll
    for (int half = 0; half < 2; ++half) {
#pragma unroll
      for (int p = 0; p < 8; ++p) {
        const float p0 = __builtin_amdgcn_exp2f(s[half][2 * p]);
        const float p1 = __builtin_amdgcn_exp2f(s[half][2 * p + 1]);
        u32 w;
        asm("v_cvt_pk_bf16_f32 %0, %1, %2" : "=v"(w) : "v"(p0), "v"(p1));
        Wd[half][p] = w;
      }
    }

    // PV: 4 k-steps of 16. A-frag (P rows q, k-window u*8) assembled by two
    // half-wave swaps. Row-sum rides the matrix pipe (ones-MFMA).
    // V frag element t*16+u*8 -> s-half t>>1, slot (t&1)*2+u, row dv.
#pragma unroll
    for (int t = 0; t < 4; ++t) {
      u32 c0 = Wd[t >> 1][(t & 1) * 4 + 0];
      u32 c1 = Wd[t >> 1][(t & 1) * 4 + 1];
      u32 c2 = Wd[t >> 1][(t & 1) * 4 + 2];
      u32 c3 = Wd[t >> 1][(t & 1) * 4 + 3];
      asm volatile("v_permlane32_swap_b32 %0, %1" : "+v"(c0), "+v"(c2));
      asm volatile("v_permlane32_swap_b32 %0, %1" : "+v"(c1), "+v"(c3));
      u32x4 wv = {c0, c1, c2, c3};
      const bf16x8 paf = __builtin_bit_cast(bf16x8, wv);
      __builtin_amdgcn_s_setprio(1);
      outsum = __builtin_amdgcn_mfma_f32_32x32x16_bf16(paf, ones, outsum, 0, 0, 0);
#pragma unroll
      for (int nb = 0; nb < 2; ++nb) {
        const int dv = nb * 32 + l32;
        const bf16x8 vf = ldb8(Vb + (t >> 1) * 2048 + dv * 32 +
                               ((((t & 1) * 2 + u) ^ ((dv >> 1) & 3)) * 8));
        outa[nb] = __builtin_amdgcn_mfma_f32_32x32x16_bf16(paf, vf, outa[nb], 0, 0, 0);
      }
      __builtin_amdgcn_s_setprio(0);
    }
  }

  // normalize + store: denominator is per-lane in outsum (same C-layout)
  const int b = bh >> 4, h = bh & 15;
#pragma unroll
  for (int r = 0; r < 16; ++r) {
    const int qr = (r & 3) + 8 * (r >> 2) + 4 * u;
    const float inv = 1.0f / outsum[r];
    const int srow = q0 + qr;
#pragma unroll
    for (int nb = 0; nb < 2; ++nb) {
      ao[((size_t)b * 2048 + srow) * 1024 + h * 64 + nb * 32 + l32] =
          __builtin_bit_cast(u16, (__bf16)(outa[nb][r] * inv));
    }
  }
}

// ---------------------------------------------------------------------------
extern "C" void kernel_launch(void* const* d_in, const int* in_sizes, int n_in,
                              void* d_out, int out_size, void* d_ws, size_t ws_size,
                              hipStream_t stream) {
  const float* q  = (const float*)d_in[0];
  const float* k  = (const float*)d_in[1];
  const float* v  = (const float*)d_in[2];
  const float* Wq = (const float*)d_in[3];
  const float* bq = (const float*)d_in[4];
  const float* Wk = (const float*)d_in[5];
  const float* bk = (const float*)d_in[6];
  const float* Wv = (const float*)d_in[7];
  const float* bv = (const float*)d_in[8];
  const float* Wo = (const float*)d_in[9];
  const float* bo = (const float*)d_in[10];

  u16* ws = (u16*)d_ws;
  u16* xq   = ws;                  // query bf16   (4M)
  u16* xk   = ws + 4194304;        // key bf16     (4M)
  u16* xv   = ws + 8388608;        // value bf16   (4M)
  u16* wqb  = ws + 12582912;       // Wq bf16      (1M)
  u16* wkb  = ws + 13631488;
  u16* wvb  = ws + 14680064;
  u16* wob  = ws + 15728640;
  u16* qperm = ws + 16777216;      // Q  [b,h,s,64]  (4M)
  u16* kperm = ws + 20971520;      // K  [b,h,s,64]  (4M)
  u16* vtp   = ws + 25165824;      // V^T[b,h,64,s]  (4M)
  u16* aout  = ws + 29360128;      // attn out [b,s,1024] (4M)
  // total: 64 MB of workspace

  convert_kernel<<<8192, 256, 0, stream>>>(q, k, v, Wq, Wk, Wv, Wo, ws);
  qkv_gemm_kernel<<<dim3(32, 8, 3), 256, 0, stream>>>(xq, xk, xv, wqb, wkb, wvb,
                                                      bq, bk, bv, qperm, kperm, vtp);
  attn_kernel<<<512, 256, 0, stream>>>(qperm, kperm, vtp, aout);
  out_gemm_kernel<<<dim3(32, 8), 256, 0, stream>>>(aout, wob, bo, (float*)d_out);
}

// Round 9
// 135.324 us; speedup vs baseline: 1.0042x; 1.0042x over previous
//
#include <hip/hip_runtime.h>

typedef unsigned short u16;
typedef unsigned int u32;
typedef __attribute__((ext_vector_type(8))) __bf16 bf16x8;
typedef __attribute__((ext_vector_type(4))) float f32x4;
typedef __attribute__((ext_vector_type(16))) float f32x16;
typedef __attribute__((ext_vector_type(4))) u32 u32x4;

#define LOG2E 1.44269504088896340736f

__device__ __forceinline__ u16 f2bf(float f) {
  u32 u = __builtin_bit_cast(u32, f);
  u += 0x7fffu + ((u >> 16) & 1u);
  return (u16)(u >> 16);
}

__device__ __forceinline__ void async_copy16(const u16* g, u16* l) {
  __builtin_amdgcn_global_load_lds((const __attribute__((address_space(1))) void*)g,
                                   (__attribute__((address_space(3))) void*)l,
                                   16, 0, 0);
}

__device__ __forceinline__ bf16x8 ldb8(const u16* p) {
  return *(const bf16x8*)p;
}

// ---------------------------------------------------------------------------
// Kernel 1: fused f32 -> bf16 conversion of [query, key, value, Wq, Wk, Wv, Wo]
// into one contiguous bf16 region (16M elements).
// ---------------------------------------------------------------------------
__global__ __launch_bounds__(256) void convert_kernel(
    const float* __restrict__ q, const float* __restrict__ k, const float* __restrict__ v,
    const float* __restrict__ wq, const float* __restrict__ wk,
    const float* __restrict__ wv, const float* __restrict__ wo,
    u16* __restrict__ out)
{
  size_t t = (size_t)blockIdx.x * 256 + threadIdx.x;  // 0 .. 2M-1
  size_t e = t * 8;
  const float* src;
  size_t off;
  if (e < 12582912) {            // 3 x 4M qkv region
    int which = (int)(e >> 22);
    src = (which == 0) ? q : ((which == 1) ? k : v);
    off = e & 4194303;
  } else {                        // 4 x 1M weight region
    size_t r = e - 12582912;
    int which = (int)(r >> 20);
    src = (which == 0) ? wq : ((which == 1) ? wk : ((which == 2) ? wv : wo));
    off = r & 1048575;
  }
  float4 f0 = *(const float4*)(src + off);
  float4 f1 = *(const float4*)(src + off + 4);
  ushort4 u0, u1;
  u0.x = f2bf(f0.x); u0.y = f2bf(f0.y); u0.z = f2bf(f0.z); u0.w = f2bf(f0.w);
  u1.x = f2bf(f1.x); u1.y = f2bf(f1.y); u1.z = f2bf(f1.z); u1.w = f2bf(f1.w);
  *(ushort4*)(out + e) = u0;
  *(ushort4*)(out + e + 4) = u1;
}

// ---------------------------------------------------------------------------
// bf16 GEMM core: C[M=4096, N=1024] = A[M,1024] @ W[N,1024]^T + bias
// R8: 128x64 tile (was 128x128) -> 2x the blocks (1536 qkv / 512 out) and
// 24 KB LDS -> 6 blocks/CU capacity, 24 waves/CU. The R5-R7 128x128 kernel
// was latency-bound with every pipe <17% busy at ~16% occupancy -- more
// concurrent waves is the only lever; intra-wave pipelining was null.
// Schedule = verified T3 minimum recipe: STAGE(t+1) at top, compute t,
// __syncthreads() at bottom (end-drain covered by compute; single barrier is
// race-free with 2 buffers because reads of buf[cur] complete before the
// barrier that releases the next iteration's write of buf[cur]).
// 4 waves (2x2): wave tile 64x32, acc 4x2, 8 MFMA + 6 ds_read_b128 per iter.
// Bank swizzle (R6-proven zero-conflict): slot cc^((row>>1)&3), pre-swizzled
// global source + same XOR on ds_read.
// MODE 0: bf16 out, permuted [b,h,s,64], value scaled by `scale`
// MODE 1: bf16 out, transposed [b,h,64,s]  (for V)
// MODE 2: f32 out, plain row-major [M,N]
// ---------------------------------------------------------------------------
template <int MODE>
__device__ __forceinline__ void gemm128x64(
    const u16* __restrict__ A, const u16* __restrict__ W,
    const float* __restrict__ bias, void* __restrict__ out,
    float scale, u16* As, u16* Bs)
{
  const int tid = threadIdx.x;
  const int wid = tid >> 6, lane = tid & 63;
  const int g = lane >> 4, l16 = lane & 15;
  const int wr = wid >> 1, wc = wid & 1;
  const int brow = blockIdx.x * 128, bcol = blockIdx.y * 64;

  f32x4 acc[4][2] = {};
  const u16* Ab = A + (size_t)brow * 1024;
  const u16* Wb = W + (size_t)bcol * 1024;

  // stage K-tile kt2 into buffer `buf`: 3 global_load_lds per thread
  // (A: 512 16B-chunks -> 2/thread; B: 256 chunks -> 1/thread).
  auto STAGE = [&](int buf, int kt2) {
    const int k0 = kt2 * 32;
    u16* Ad = As + buf * 4096;
    u16* Bd = Bs + buf * 2048;
#pragma unroll
    for (int i = 0; i < 2; ++i) {
      const int chunk = i * 256 + wid * 64 + lane;
      const int row = chunk >> 2, cc = chunk & 3;
      const int sc = (cc ^ ((row >> 1) & 3)) * 8;   // pre-swizzled source chunk
      async_copy16(Ab + (size_t)row * 1024 + k0 + sc, Ad + (i * 256 + wid * 64) * 8);
    }
    {
      const int chunk = wid * 64 + lane;
      const int row = chunk >> 2, cc = chunk & 3;
      const int sc = (cc ^ ((row >> 1) & 3)) * 8;
      async_copy16(Wb + (size_t)row * 1024 + k0 + sc, Bd + (wid * 64) * 8);
    }
  };

  STAGE(0, 0);
  __syncthreads();

  for (int kt = 0; kt < 32; ++kt) {
    if (kt < 31) STAGE((kt + 1) & 1, kt + 1);   // prefetch next tile (async)

    const u16* Ac = As + (kt & 1) * 4096;
    const u16* Bc = Bs + (kt & 1) * 2048;

    bf16x8 a[4], b[2];
#pragma unroll
    for (int m = 0; m < 4; ++m) {
      const int row = wr * 64 + m * 16 + l16;
      a[m] = ldb8(Ac + row * 32 + ((g ^ ((row >> 1) & 3)) * 8));
    }
#pragma unroll
    for (int n = 0; n < 2; ++n) {
      const int row = wc * 32 + n * 16 + l16;
      b[n] = ldb8(Bc + row * 32 + ((g ^ ((row >> 1) & 3)) * 8));
    }
#pragma unroll
    for (int m = 0; m < 4; ++m)
#pragma unroll
      for (int n = 0; n < 2; ++n)
        acc[m][n] = __builtin_amdgcn_mfma_f32_16x16x32_bf16(a[m], b[n], acc[m][n], 0, 0, 0);

    __syncthreads();  // drains vmcnt (stage kt+1, issued a full compute ago) + lgkm
  }

  // epilogue
#pragma unroll
  for (int m = 0; m < 4; ++m) {
    const int mg = brow + wr * 64 + m * 16 + g * 4;  // + j
#pragma unroll
    for (int n = 0; n < 2; ++n) {
      const int cg = bcol + wc * 32 + n * 16 + l16;
      const float bb = bias[cg];
      if constexpr (MODE == 0) {
        const int h = cg >> 6, d = cg & 63;
#pragma unroll
        for (int j = 0; j < 4; ++j) {
          const int row = mg + j;
          const int bb_ = row >> 11, s = row & 2047;
          ((u16*)out)[(((size_t)(bb_ * 16 + h) * 2048 + s) << 6) + d] =
              f2bf((acc[m][n][j] + bb) * scale);
        }
      } else if constexpr (MODE == 1) {
        const int h = cg >> 6, d = cg & 63;
        const int bb_ = mg >> 11, s0 = mg & 2047;
        ushort4 pk;
        pk.x = f2bf(acc[m][n][0] + bb);
        pk.y = f2bf(acc[m][n][1] + bb);
        pk.z = f2bf(acc[m][n][2] + bb);
        pk.w = f2bf(acc[m][n][3] + bb);
        *(ushort4*)((u16*)out + ((size_t)(bb_ * 16 + h) * 64 + d) * 2048 + s0) = pk;
      } else {
#pragma unroll
        for (int j = 0; j < 4; ++j) {
          const int row = mg + j;
          ((float*)out)[(size_t)row * 1024 + cg] = acc[m][n][j] + bb;
        }
      }
    }
  }
}

__global__ __launch_bounds__(256) void qkv_gemm_kernel(
    const u16* __restrict__ xq, const u16* __restrict__ xk, const u16* __restrict__ xv,
    const u16* __restrict__ wq, const u16* __restrict__ wk, const u16* __restrict__ wv,
    const float* __restrict__ bq, const float* __restrict__ bk, const float* __restrict__ bv,
    u16* __restrict__ oq, u16* __restrict__ ok, u16* __restrict__ ov)
{
  __shared__ u16 As[2][4096];
  __shared__ u16 Bs[2][2048];
  const int z = blockIdx.z;
  // Q pre-scaled by 1/sqrt(64) * log2(e): attention then uses p = exp2(s) directly.
  if (z == 0)      gemm128x64<0>(xq, wq, bq, oq, 0.125f * LOG2E, &As[0][0], &Bs[0][0]);
  else if (z == 1) gemm128x64<0>(xk, wk, bk, ok, 1.0f, &As[0][0], &Bs[0][0]);    // K
  else             gemm128x64<1>(xv, wv, bv, ov, 1.0f, &As[0][0], &Bs[0][0]);    // V transposed
}

__global__ __launch_bounds__(256) void out_gemm_kernel(
    const u16* __restrict__ a, const u16* __restrict__ w,
    const float* __restrict__ bias, float* __restrict__ o)
{
  __shared__ u16 As[2][4096];
  __shared__ u16 Bs[2][2048];
  gemm128x64<2>(a, w, bias, o, 1.0f, &As[0][0], &Bs[0][0]);
}

// ---------------------------------------------------------------------------
// Kernel 3: flash attention, 32x32x16 MFMA, swapped QK^T (T12), in-register P
// via v_cvt_pk_bf16_f32 + 2 x v_permlane32_swap_b32 per k-step, fixed-max
// softmax, row-sum on the matrix pipe (ones-MFMA), s_setprio, depth-2
// prefetch with 4 LDS buffers and counted vmcnt. K/V tiles as two
// 64-byte-row half-tiles [2][64][32] with the zero-conflict swizzle.
// Grid 512 (XCD-chunked: each XCD owns 4 whole heads), 4 waves x 32 q-rows.
// ---------------------------------------------------------------------------
__global__ __launch_bounds__(256) void attn_kernel(
    const u16* __restrict__ qp, const u16* __restrict__ kp,
    const u16* __restrict__ vt, u16* __restrict__ ao)
{
  __shared__ u16 Kbuf[4][4096];      // [4][2 d-half][64 k][32] bf16, 8 KB each
  __shared__ u16 Vbuf[4][4096];      // [4][2 s-half][64 d][32] bf16, 8 KB each

  const int wid = threadIdx.x >> 6, lane = threadIdx.x & 63;
  const int u = lane >> 5, l32 = lane & 31;

  // XCD-chunked remap: 512 blocks, 8 XCDs -> each XCD owns 4 whole heads.
  int bid = (int)blockIdx.x;
  bid = (bid & 7) * 64 + (bid >> 3);
  const int bh = bid >> 4;                 // b*16 + h
  const int q0 = (bid & 15) * 128 + wid * 32;

  const u16* Q = qp + ((size_t)bh * 2048 + q0) * 64;
  const u16* K = kp + (size_t)bh * 2048 * 64;
  const u16* V = vt + (size_t)bh * 64 * 2048;

  // Q as B-fragments: col = q = l32, k-window = u*8 within each 16-d step
  bf16x8 aq[4];
#pragma unroll
  for (int st = 0; st < 4; ++st)
    aq[st] = ldb8(Q + l32 * 64 + st * 16 + u * 8);

  f32x16 outa[2] = {};   // C[q_row][d=nb*32+l32]
  f32x16 outsum = {};    // C[q_row][*] = running row-sum of P (denominator)
  f32x16 zf16 = {};

  const __bf16 one_bf = (__bf16)1.0f;
  bf16x8 ones = {one_bf, one_bf, one_bf, one_bf, one_bf, one_bf, one_bf, one_bf};

  // stage tile kb into buffer `buf`: 4 global_load_lds per thread (2 K + 2 V).
  // LDS layout [half][row][32] per matrix; chunk c = half*256 + row*4 + slot;
  // linear LDS dest, pre-swizzled global source slot sc = slot^((row>>1)&3).
  auto STAGE = [&](int buf, int kb) {
#pragma unroll
    for (int i = 0; i < 2; ++i) {
      const int c = i * 256 + wid * 64 + lane;   // i == half
      const int row = (c & 255) >> 2, slot = c & 3;
      const int sc = (slot ^ ((row >> 1) & 3)) * 8;
      const int lbase = (i * 256 + wid * 64) * 8;  // elements; HW adds lane*16B
      async_copy16(K + (size_t)(kb + row) * 64 + i * 32 + sc, &Kbuf[buf][lbase]);
      async_copy16(V + (size_t)row * 2048 + kb + i * 32 + sc, &Vbuf[buf][lbase]);
    }
  };

  STAGE(0, 0);
  STAGE(1, 64);

  for (int kt = 0; kt < 32; ++kt) {
    // T4: counted vmcnt -- wait only for stage kt (4 loads/thread/stage).
    if (kt < 30) {
      STAGE((kt + 2) & 3, (kt + 2) * 64);
      asm volatile("s_waitcnt vmcnt(8)" ::: "memory");
    } else if (kt == 30) {
      asm volatile("s_waitcnt vmcnt(4)" ::: "memory");
    } else {
      asm volatile("s_waitcnt vmcnt(0)" ::: "memory");
    }
    __builtin_amdgcn_s_barrier();
    asm volatile("" ::: "memory");  // pin ds_reads below the barrier

    const u16* Kb = Kbuf[kt & 3];
    const u16* Vb = Vbuf[kt & 3];

    // Swapped QK^T: s[half] = K[half*32..+31][:] . Q -> P[k][q=l32]
    // k = half*32 + (reg&3) + 8*(reg>>2) + 4u
    // K frag element st*16+u*8 -> d-half st>>1, slot (st&1)*2+u, row krow.
    f32x16 s[2];
    __builtin_amdgcn_s_setprio(1);
#pragma unroll
    for (int half = 0; half < 2; ++half) {
      const int krow = half * 32 + l32;
#pragma unroll
      for (int st = 0; st < 4; ++st) {
        const bf16x8 kf = ldb8(Kb + (st >> 1) * 2048 + krow * 32 +
                               ((((st & 1) * 2 + u) ^ ((krow >> 1) & 3)) * 8));
        s[half] = __builtin_amdgcn_mfma_f32_32x32x16_bf16(
            kf, aq[st], (st == 0) ? zf16 : s[half], 0, 0, 0);
      }
    }
    __builtin_amdgcn_s_setprio(0);

    // p = exp2(s); pack adjacent-k pairs to one bf16x2 word per cvt_pk inst
    u32 Wd[2][8];
#pragma unroll
    for (int half = 0; half < 2; ++half) {
#pragma unroll
      for (int p = 0; p < 8; ++p) {
        const float p0 = __builtin_amdgcn_exp2f(s[half][2 * p]);
        const float p1 = __builtin_amdgcn_exp2f(s[half][2 * p + 1]);
        u32 w;
        asm("v_cvt_pk_bf16_f32 %0, %1, %2" : "=v"(w) : "v"(p0), "v"(p1));
        Wd[half][p] = w;
      }
    }

    // PV: 4 k-steps of 16. A-frag (P rows q, k-window u*8) assembled by two
    // half-wave swaps. Row-sum rides the matrix pipe (ones-MFMA).
    // V frag element t*16+u*8 -> s-half t>>1, slot (t&1)*2+u, row dv.
#pragma unroll
    for (int t = 0; t < 4; ++t) {
      u32 c0 = Wd[t >> 1][(t & 1) * 4 + 0];
      u32 c1 = Wd[t >> 1][(t & 1) * 4 + 1];
      u32 c2 = Wd[t >> 1][(t & 1) * 4 + 2];
      u32 c3 = Wd[t >> 1][(t & 1) * 4 + 3];
      asm volatile("v_permlane32_swap_b32 %0, %1" : "+v"(c0), "+v"(c2));
      asm volatile("v_permlane32_swap_b32 %0, %1" : "+v"(c1), "+v"(c3));
      u32x4 wv = {c0, c1, c2, c3};
      const bf16x8 paf = __builtin_bit_cast(bf16x8, wv);
      __builtin_amdgcn_s_setprio(1);
      outsum = __builtin_amdgcn_mfma_f32_32x32x16_bf16(paf, ones, outsum, 0, 0, 0);
#pragma unroll
      for (int nb = 0; nb < 2; ++nb) {
        const int dv = nb * 32 + l32;
        const bf16x8 vf = ldb8(Vb + (t >> 1) * 2048 + dv * 32 +
                               ((((t & 1) * 2 + u) ^ ((dv >> 1) & 3)) * 8));
        outa[nb] = __builtin_amdgcn_mfma_f32_32x32x16_bf16(paf, vf, outa[nb], 0, 0, 0);
      }
      __builtin_amdgcn_s_setprio(0);
    }
  }

  // normalize + store: denominator is per-lane in outsum (same C-layout)
  const int b = bh >> 4, h = bh & 15;
#pragma unroll
  for (int r = 0; r < 16; ++r) {
    const int qr = (r & 3) + 8 * (r >> 2) + 4 * u;
    const float inv = 1.0f / outsum[r];
    const int srow = q0 + qr;
#pragma unroll
    for (int nb = 0; nb < 2; ++nb) {
      ao[((size_t)b * 2048 + srow) * 1024 + h * 64 + nb * 32 + l32] =
          __builtin_bit_cast(u16, (__bf16)(outa[nb][r] * inv));
    }
  }
}

// ---------------------------------------------------------------------------
extern "C" void kernel_launch(void* const* d_in, const int* in_sizes, int n_in,
                              void* d_out, int out_size, void* d_ws, size_t ws_size,
                              hipStream_t stream) {
  const float* q  = (const float*)d_in[0];
  const float* k  = (const float*)d_in[1];
  const float* v  = (const float*)d_in[2];
  const float* Wq = (const float*)d_in[3];
  const float* bq = (const float*)d_in[4];
  const float* Wk = (const float*)d_in[5];
  const float* bk = (const float*)d_in[6];
  const float* Wv = (const float*)d_in[7];
  const float* bv = (const float*)d_in[8];
  const float* Wo = (const float*)d_in[9];
  const float* bo = (const float*)d_in[10];

  u16* ws = (u16*)d_ws;
  u16* xq   = ws;                  // query bf16   (4M)
  u16* xk   = ws + 4194304;        // key bf16     (4M)
  u16* xv   = ws + 8388608;        // value bf16   (4M)
  u16* wqb  = ws + 12582912;       // Wq bf16      (1M)
  u16* wkb  = ws + 13631488;
  u16* wvb  = ws + 14680064;
  u16* wob  = ws + 15728640;
  u16* qperm = ws + 16777216;      // Q  [b,h,s,64]  (4M)
  u16* kperm = ws + 20971520;      // K  [b,h,s,64]  (4M)
  u16* vtp   = ws + 25165824;      // V^T[b,h,64,s]  (4M)
  u16* aout  = ws + 29360128;      // attn out [b,s,1024] (4M)
  // total: 64 MB of workspace

  convert_kernel<<<8192, 256, 0, stream>>>(q, k, v, Wq, Wk, Wv, Wo, ws);
  qkv_gemm_kernel<<<dim3(32, 16, 3), 256, 0, stream>>>(xq, xk, xv, wqb, wkb, wvb,
                                                       bq, bk, bv, qperm, kperm, vtp);
  attn_kernel<<<512, 256, 0, stream>>>(qperm, kperm, vtp, aout);
  out_gemm_kernel<<<dim3(32, 16), 256, 0, stream>>>(aout, wob, bo, (float*)d_out);
}

// Round 10
// 130.931 us; speedup vs baseline: 1.0378x; 1.0336x over previous
//
#include <hip/hip_runtime.h>

typedef unsigned short u16;
typedef unsigned int u32;
typedef __attribute__((ext_vector_type(8))) __bf16 bf16x8;
typedef __attribute__((ext_vector_type(4))) float f32x4;
typedef __attribute__((ext_vector_type(16))) float f32x16;
typedef __attribute__((ext_vector_type(4))) u32 u32x4;

#define LOG2E 1.44269504088896340736f

__device__ __forceinline__ u16 f2bf(float f) {
  u32 u = __builtin_bit_cast(u32, f);
  u += 0x7fffu + ((u >> 16) & 1u);
  return (u16)(u >> 16);
}

__device__ __forceinline__ void async_copy16(const u16* g, u16* l) {
  __builtin_amdgcn_global_load_lds((const __attribute__((address_space(1))) void*)g,
                                   (__attribute__((address_space(3))) void*)l,
                                   16, 0, 0);
}

__device__ __forceinline__ bf16x8 ldb8(const u16* p) {
  return *(const bf16x8*)p;
}

// ---------------------------------------------------------------------------
// Kernel 1: fused f32 -> bf16 conversion of [query, key, value, Wq, Wk, Wv, Wo]
// into one contiguous bf16 region (16M elements).
// ---------------------------------------------------------------------------
__global__ __launch_bounds__(256) void convert_kernel(
    const float* __restrict__ q, const float* __restrict__ k, const float* __restrict__ v,
    const float* __restrict__ wq, const float* __restrict__ wk,
    const float* __restrict__ wv, const float* __restrict__ wo,
    u16* __restrict__ out)
{
  size_t t = (size_t)blockIdx.x * 256 + threadIdx.x;  // 0 .. 2M-1
  size_t e = t * 8;
  const float* src;
  size_t off;
  if (e < 12582912) {            // 3 x 4M qkv region
    int which = (int)(e >> 22);
    src = (which == 0) ? q : ((which == 1) ? k : v);
    off = e & 4194303;
  } else {                        // 4 x 1M weight region
    size_t r = e - 12582912;
    int which = (int)(r >> 20);
    src = (which == 0) ? wq : ((which == 1) ? wk : ((which == 2) ? wv : wo));
    off = r & 1048575;
  }
  float4 f0 = *(const float4*)(src + off);
  float4 f1 = *(const float4*)(src + off + 4);
  ushort4 u0, u1;
  u0.x = f2bf(f0.x); u0.y = f2bf(f0.y); u0.z = f2bf(f0.z); u0.w = f2bf(f0.w);
  u1.x = f2bf(f1.x); u1.y = f2bf(f1.y); u1.z = f2bf(f1.z); u1.w = f2bf(f1.w);
  *(ushort4*)(out + e) = u0;
  *(ushort4*)(out + e + 4) = u1;
}

// ---------------------------------------------------------------------------
// bf16 GEMM core: C[M=4096, N=1024] = A[M,1024] @ W[N,1024]^T + bias
// 128x64 tile, 2-buf, BK=32, 4 waves (2x2), 16x16x32 MFMA. T3 minimum recipe:
// STAGE(t+1) at top, compute t, __syncthreads() at bottom. Zero-conflict bank
// swizzle: slot cc^((row>>1)&3), pre-swizzled global source + same XOR on read.
// MODE 0: bf16 out, permuted [b,h,s,64], value scaled by `scale`
// MODE 1: bf16 out, transposed [b,h,64,s]  (for V)
// MODE 2: f32 out, plain row-major [M,N]
// ---------------------------------------------------------------------------
template <int MODE>
__device__ __forceinline__ void gemm128x64(
    const u16* __restrict__ A, const u16* __restrict__ W,
    const float* __restrict__ bias, void* __restrict__ out,
    float scale, u16* As, u16* Bs)
{
  const int tid = threadIdx.x;
  const int wid = tid >> 6, lane = tid & 63;
  const int g = lane >> 4, l16 = lane & 15;
  const int wr = wid >> 1, wc = wid & 1;
  const int brow = blockIdx.x * 128, bcol = blockIdx.y * 64;

  f32x4 acc[4][2] = {};
  const u16* Ab = A + (size_t)brow * 1024;
  const u16* Wb = W + (size_t)bcol * 1024;

  auto STAGE = [&](int buf, int kt2) {
    const int k0 = kt2 * 32;
    u16* Ad = As + buf * 4096;
    u16* Bd = Bs + buf * 2048;
#pragma unroll
    for (int i = 0; i < 2; ++i) {
      const int chunk = i * 256 + wid * 64 + lane;
      const int row = chunk >> 2, cc = chunk & 3;
      const int sc = (cc ^ ((row >> 1) & 3)) * 8;   // pre-swizzled source chunk
      async_copy16(Ab + (size_t)row * 1024 + k0 + sc, Ad + (i * 256 + wid * 64) * 8);
    }
    {
      const int chunk = wid * 64 + lane;
      const int row = chunk >> 2, cc = chunk & 3;
      const int sc = (cc ^ ((row >> 1) & 3)) * 8;
      async_copy16(Wb + (size_t)row * 1024 + k0 + sc, Bd + (wid * 64) * 8);
    }
  };

  STAGE(0, 0);
  __syncthreads();

  for (int kt = 0; kt < 32; ++kt) {
    if (kt < 31) STAGE((kt + 1) & 1, kt + 1);   // prefetch next tile (async)

    const u16* Ac = As + (kt & 1) * 4096;
    const u16* Bc = Bs + (kt & 1) * 2048;

    bf16x8 a[4], b[2];
#pragma unroll
    for (int m = 0; m < 4; ++m) {
      const int row = wr * 64 + m * 16 + l16;
      a[m] = ldb8(Ac + row * 32 + ((g ^ ((row >> 1) & 3)) * 8));
    }
#pragma unroll
    for (int n = 0; n < 2; ++n) {
      const int row = wc * 32 + n * 16 + l16;
      b[n] = ldb8(Bc + row * 32 + ((g ^ ((row >> 1) & 3)) * 8));
    }
#pragma unroll
    for (int m = 0; m < 4; ++m)
#pragma unroll
      for (int n = 0; n < 2; ++n)
        acc[m][n] = __builtin_amdgcn_mfma_f32_16x16x32_bf16(a[m], b[n], acc[m][n], 0, 0, 0);

    __syncthreads();  // drains vmcnt (stage kt+1, issued a full compute ago) + lgkm
  }

  // epilogue
#pragma unroll
  for (int m = 0; m < 4; ++m) {
    const int mg = brow + wr * 64 + m * 16 + g * 4;  // + j
#pragma unroll
    for (int n = 0; n < 2; ++n) {
      const int cg = bcol + wc * 32 + n * 16 + l16;
      const float bb = bias[cg];
      if constexpr (MODE == 0) {
        const int h = cg >> 6, d = cg & 63;
#pragma unroll
        for (int j = 0; j < 4; ++j) {
          const int row = mg + j;
          const int bb_ = row >> 11, s = row & 2047;
          ((u16*)out)[(((size_t)(bb_ * 16 + h) * 2048 + s) << 6) + d] =
              f2bf((acc[m][n][j] + bb) * scale);
        }
      } else if constexpr (MODE == 1) {
        const int h = cg >> 6, d = cg & 63;
        const int bb_ = mg >> 11, s0 = mg & 2047;
        ushort4 pk;
        pk.x = f2bf(acc[m][n][0] + bb);
        pk.y = f2bf(acc[m][n][1] + bb);
        pk.z = f2bf(acc[m][n][2] + bb);
        pk.w = f2bf(acc[m][n][3] + bb);
        *(ushort4*)((u16*)out + ((size_t)(bb_ * 16 + h) * 64 + d) * 2048 + s0) = pk;
      } else {
#pragma unroll
        for (int j = 0; j < 4; ++j) {
          const int row = mg + j;
          ((float*)out)[(size_t)row * 1024 + cg] = acc[m][n][j] + bb;
        }
      }
    }
  }
}

__global__ __launch_bounds__(256) void qkv_gemm_kernel(
    const u16* __restrict__ xq, const u16* __restrict__ xk, const u16* __restrict__ xv,
    const u16* __restrict__ wq, const u16* __restrict__ wk, const u16* __restrict__ wv,
    const float* __restrict__ bq, const float* __restrict__ bk, const float* __restrict__ bv,
    u16* __restrict__ oq, u16* __restrict__ ok, u16* __restrict__ ov)
{
  __shared__ u16 As[2][4096];
  __shared__ u16 Bs[2][2048];
  const int z = blockIdx.z;
  // Q pre-scaled by 1/sqrt(64) * log2(e): attention then uses p = exp2(s) directly.
  if (z == 0)      gemm128x64<0>(xq, wq, bq, oq, 0.125f * LOG2E, &As[0][0], &Bs[0][0]);
  else if (z == 1) gemm128x64<0>(xk, wk, bk, ok, 1.0f, &As[0][0], &Bs[0][0]);    // K
  else             gemm128x64<1>(xv, wv, bv, ov, 1.0f, &As[0][0], &Bs[0][0]);    // V transposed
}

__global__ __launch_bounds__(256) void out_gemm_kernel(
    const u16* __restrict__ a, const u16* __restrict__ w,
    const float* __restrict__ bias, float* __restrict__ o)
{
  __shared__ u16 As[2][4096];
  __shared__ u16 Bs[2][2048];
  gemm128x64<2>(a, w, bias, o, 1.0f, &As[0][0], &Bs[0][0]);
}

// ---------------------------------------------------------------------------
// Kernel 3: flash attention, R10: 8 waves (512 threads), KV-SEQUENCE SPLIT.
// Wave pair {w, w+4} owns the same 32 q-rows; waves 0-3 process EVEN KV tiles,
// waves 4-7 ODD tiles, concurrently between the same barriers -> per-wave
// serial chain halves and waves/CU doubles (16, 4/SIMD). Fixed-max softmax
// makes the combine exact: O = O_even + O_odd, l = l_even + l_odd (no max
// rescale), done once at the end through LDS (reusing K/V buffers).
// Staging: 1 load/thread/tile; tile pair per super-iter, STAGE issued AFTER
// the barrier (write target provably idle; loads are one-full-compute old at
// the next __syncthreads, so the implicit vmcnt(0) is nearly free).
// 32x32x16 MFMA swapped QK^T, in-register P via cvt_pk + permlane32_swap,
// row-sum on the matrix pipe (ones-MFMA). Grid 512 (XCD-chunked).
// ---------------------------------------------------------------------------
__global__ __launch_bounds__(512) void attn_kernel(
    const u16* __restrict__ qp, const u16* __restrict__ kp,
    const u16* __restrict__ vt, u16* __restrict__ ao)
{
  __shared__ u16 Kbuf[4][4096];      // [4][2 d-half][64 k][32] bf16, 8 KB each
  __shared__ u16 Vbuf[4][4096];      // [4][2 s-half][64 d][32] bf16, 8 KB each

  const int tid = threadIdx.x;
  const int wid = tid >> 6, lane = tid & 63;
  const int u = lane >> 5, l32 = lane & 31;
  const int wsub = wid & 3, g2 = wid >> 2;   // q-tile owner / KV parity group

  // XCD-chunked remap: 512 blocks, 8 XCDs -> each XCD owns 4 whole heads.
  int bid = (int)blockIdx.x;
  bid = (bid & 7) * 64 + (bid >> 3);
  const int bh = bid >> 4;                 // b*16 + h
  const int q0 = (bid & 15) * 128 + wsub * 32;

  const u16* Q = qp + ((size_t)bh * 2048 + q0) * 64;
  const u16* K = kp + (size_t)bh * 2048 * 64;
  const u16* V = vt + (size_t)bh * 64 * 2048;

  // Q as B-fragments: col = q = l32, k-window = u*8 within each 16-d step
  bf16x8 aq[4];
#pragma unroll
  for (int st = 0; st < 4; ++st)
    aq[st] = ldb8(Q + l32 * 64 + st * 16 + u * 8);

  f32x16 outa[2] = {};   // C[q_row][d=nb*32+l32] (partial: this wave's tiles)
  f32x16 outsum = {};    // C[q_row][*] = partial row-sum of P (denominator)
  f32x16 zf16 = {};

  const __bf16 one_bf = (__bf16)1.0f;
  bf16x8 ones = {one_bf, one_bf, one_bf, one_bf, one_bf, one_bf, one_bf, one_bf};

  // stage ONE tile (512 threads, 1 K-load + 1 V-load per thread).
  // LDS layout [half][row][32] per matrix; chunk c = tid = half*256+row*4+slot;
  // linear LDS dest, pre-swizzled global source slot sc = slot^((row>>1)&3).
  auto STAGE1 = [&](int buf, int kb) {
    const int half = tid >> 8, row = (tid & 255) >> 2, slot = tid & 3;
    const int sc = (slot ^ ((row >> 1) & 3)) * 8;
    async_copy16(K + (size_t)(kb + row) * 64 + half * 32 + sc, &Kbuf[buf][wid * 512]);
    async_copy16(V + (size_t)row * 2048 + kb + half * 32 + sc, &Vbuf[buf][wid * 512]);
  };

  STAGE1(0, 0);      // tile 0
  STAGE1(1, 64);     // tile 1

  for (int T = 0; T < 16; ++T) {
    // barrier: (a) all reads of pair T-1 done -> pair T+1's buffers are free,
    // (b) implicit vmcnt(0) drains pair T's stage (issued one full compute ago).
    __syncthreads();
    if (T < 15) {
      STAGE1((2 * T + 2) & 3, (2 * T + 2) * 64);
      STAGE1((2 * T + 3) & 3, (2 * T + 3) * 64);
    }

    const int kt = 2 * T + g2;   // group 0: even tiles, group 1: odd tiles
    const u16* Kb = Kbuf[kt & 3];
    const u16* Vb = Vbuf[kt & 3];

    // Swapped QK^T: s[half] = K[half*32..+31][:] . Q -> P[k][q=l32]
    // k = half*32 + (reg&3) + 8*(reg>>2) + 4u
    f32x16 s[2];
    __builtin_amdgcn_s_setprio(1);
#pragma unroll
    for (int half = 0; half < 2; ++half) {
      const int krow = half * 32 + l32;
#pragma unroll
      for (int st = 0; st < 4; ++st) {
        const bf16x8 kf = ldb8(Kb + (st >> 1) * 2048 + krow * 32 +
                               ((((st & 1) * 2 + u) ^ ((krow >> 1) & 3)) * 8));
        s[half] = __builtin_amdgcn_mfma_f32_32x32x16_bf16(
            kf, aq[st], (st == 0) ? zf16 : s[half], 0, 0, 0);
      }
    }
    __builtin_amdgcn_s_setprio(0);

    // p = exp2(s); pack adjacent-k pairs to one bf16x2 word per cvt_pk inst
    u32 Wd[2][8];
#pragma unroll
    for (int half = 0; half < 2; ++half) {
#pragma unroll
      for (int p = 0; p < 8; ++p) {
        const float p0 = __builtin_amdgcn_exp2f(s[half][2 * p]);
        const float p1 = __builtin_amdgcn_exp2f(s[half][2 * p + 1]);
        u32 w;
        asm("v_cvt_pk_bf16_f32 %0, %1, %2" : "=v"(w) : "v"(p0), "v"(p1));
        Wd[half][p] = w;
      }
    }

    // PV: 4 k-steps of 16. A-frag assembled by two half-wave swaps.
    // Row-sum rides the matrix pipe (ones-MFMA).
#pragma unroll
    for (int t = 0; t < 4; ++t) {
      u32 c0 = Wd[t >> 1][(t & 1) * 4 + 0];
      u32 c1 = Wd[t >> 1][(t & 1) * 4 + 1];
      u32 c2 = Wd[t >> 1][(t & 1) * 4 + 2];
      u32 c3 = Wd[t >> 1][(t & 1) * 4 + 3];
      asm volatile("v_permlane32_swap_b32 %0, %1" : "+v"(c0), "+v"(c2));
      asm volatile("v_permlane32_swap_b32 %0, %1" : "+v"(c1), "+v"(c3));
      u32x4 wv = {c0, c1, c2, c3};
      const bf16x8 paf = __builtin_bit_cast(bf16x8, wv);
      __builtin_amdgcn_s_setprio(1);
      outsum = __builtin_amdgcn_mfma_f32_32x32x16_bf16(paf, ones, outsum, 0, 0, 0);
#pragma unroll
      for (int nb = 0; nb < 2; ++nb) {
        const int dv = nb * 32 + l32;
        const bf16x8 vf = ldb8(Vb + (t >> 1) * 2048 + dv * 32 +
                               ((((t & 1) * 2 + u) ^ ((dv >> 1) & 3)) * 8));
        outa[nb] = __builtin_amdgcn_mfma_f32_32x32x16_bf16(paf, vf, outa[nb], 0, 0, 0);
      }
      __builtin_amdgcn_s_setprio(0);
    }
  }

  // ---- exact combine: waves 4-7 publish partials, waves 0-3 add + store ----
  __syncthreads();   // all compute reads done; K/V buffers reusable
  float* exA = (float*)&Kbuf[0][0];   // 4 waves x 8 KB  = 32 KB (outa)
  float* exS = (float*)&Vbuf[0][0];   // 4 waves x 4 KB  = 16 KB (outsum)
  if (wid >= 4) {
    const int ba = (wid - 4) * 2048 + lane * 32;
#pragma unroll
    for (int nb = 0; nb < 2; ++nb)
#pragma unroll
      for (int r = 0; r < 16; ++r) exA[ba + nb * 16 + r] = outa[nb][r];
    const int bs = (wid - 4) * 1024 + lane * 16;
#pragma unroll
    for (int r = 0; r < 16; ++r) exS[bs + r] = outsum[r];
  }
  __syncthreads();
  if (wid < 4) {
    const int ba = wid * 2048 + lane * 32;
#pragma unroll
    for (int nb = 0; nb < 2; ++nb)
#pragma unroll
      for (int r = 0; r < 16; ++r) outa[nb][r] += exA[ba + nb * 16 + r];
    const int bs = wid * 1024 + lane * 16;
#pragma unroll
    for (int r = 0; r < 16; ++r) outsum[r] += exS[bs + r];

    const int b = bh >> 4, h = bh & 15;
#pragma unroll
    for (int r = 0; r < 16; ++r) {
      const int qr = (r & 3) + 8 * (r >> 2) + 4 * u;
      const float inv = 1.0f / outsum[r];
      const int srow = q0 + qr;
#pragma unroll
      for (int nb = 0; nb < 2; ++nb) {
        ao[((size_t)b * 2048 + srow) * 1024 + h * 64 + nb * 32 + l32] =
            __builtin_bit_cast(u16, (__bf16)(outa[nb][r] * inv));
      }
    }
  }
}

// ---------------------------------------------------------------------------
extern "C" void kernel_launch(void* const* d_in, const int* in_sizes, int n_in,
                              void* d_out, int out_size, void* d_ws, size_t ws_size,
                              hipStream_t stream) {
  const float* q  = (const float*)d_in[0];
  const float* k  = (const float*)d_in[1];
  const float* v  = (const float*)d_in[2];
  const float* Wq = (const float*)d_in[3];
  const float* bq = (const float*)d_in[4];
  const float* Wk = (const float*)d_in[5];
  const float* bk = (const float*)d_in[6];
  const float* Wv = (const float*)d_in[7];
  const float* bv = (const float*)d_in[8];
  const float* Wo = (const float*)d_in[9];
  const float* bo = (const float*)d_in[10];

  u16* ws = (u16*)d_ws;
  u16* xq   = ws;                  // query bf16   (4M)
  u16* xk   = ws + 4194304;        // key bf16     (4M)
  u16* xv   = ws + 8388608;        // value bf16   (4M)
  u16* wqb  = ws + 12582912;       // Wq bf16      (1M)
  u16* wkb  = ws + 13631488;
  u16* wvb  = ws + 14680064;
  u16* wob  = ws + 15728640;
  u16* qperm = ws + 16777216;      // Q  [b,h,s,64]  (4M)
  u16* kperm = ws + 20971520;      // K  [b,h,s,64]  (4M)
  u16* vtp   = ws + 25165824;      // V^T[b,h,64,s]  (4M)
  u16* aout  = ws + 29360128;      // attn out [b,s,1024] (4M)
  // total: 64 MB of workspace

  convert_kernel<<<8192, 256, 0, stream>>>(q, k, v, Wq, Wk, Wv, Wo, ws);
  qkv_gemm_kernel<<<dim3(32, 16, 3), 256, 0, stream>>>(xq, xk, xv, wqb, wkb, wvb,
                                                       bq, bk, bv, qperm, kperm, vtp);
  attn_kernel<<<512, 512, 0, stream>>>(qperm, kperm, vtp, aout);
  out_gemm_kernel<<<dim3(32, 16), 256, 0, stream>>>(aout, wob, bo, (float*)d_out);
}

// Round 11
// 112.901 us; speedup vs baseline: 1.2036x; 1.1597x over previous
//
#include <hip/hip_runtime.h>

typedef unsigned short u16;
typedef unsigned int u32;
typedef __attribute__((ext_vector_type(8))) __bf16 bf16x8;
typedef __attribute__((ext_vector_type(4))) float f32x4;
typedef __attribute__((ext_vector_type(16))) float f32x16;
typedef __attribute__((ext_vector_type(4))) u32 u32x4;

#define LOG2E 1.44269504088896340736f

__device__ __forceinline__ u16 f2bf(float f) {
  u32 u = __builtin_bit_cast(u32, f);
  u += 0x7fffu + ((u >> 16) & 1u);
  return (u16)(u >> 16);
}

__device__ __forceinline__ void async_copy16(const u16* g, u16* l) {
  __builtin_amdgcn_global_load_lds((const __attribute__((address_space(1))) void*)g,
                                   (__attribute__((address_space(3))) void*)l,
                                   16, 0, 0);
}

__device__ __forceinline__ bf16x8 ldb8(const u16* p) {
  return *(const bf16x8*)p;
}

// ---------------------------------------------------------------------------
// Kernel 1: fused f32 -> bf16 conversion of [query, key, value, Wq, Wk, Wv, Wo]
// into one contiguous bf16 region (16M elements).
// ---------------------------------------------------------------------------
__global__ __launch_bounds__(256) void convert_kernel(
    const float* __restrict__ q, const float* __restrict__ k, const float* __restrict__ v,
    const float* __restrict__ wq, const float* __restrict__ wk,
    const float* __restrict__ wv, const float* __restrict__ wo,
    u16* __restrict__ out)
{
  size_t t = (size_t)blockIdx.x * 256 + threadIdx.x;  // 0 .. 2M-1
  size_t e = t * 8;
  const float* src;
  size_t off;
  if (e < 12582912) {            // 3 x 4M qkv region
    int which = (int)(e >> 22);
    src = (which == 0) ? q : ((which == 1) ? k : v);
    off = e & 4194303;
  } else {                        // 4 x 1M weight region
    size_t r = e - 12582912;
    int which = (int)(r >> 20);
    src = (which == 0) ? wq : ((which == 1) ? wk : ((which == 2) ? wv : wo));
    off = r & 1048575;
  }
  float4 f0 = *(const float4*)(src + off);
  float4 f1 = *(const float4*)(src + off + 4);
  ushort4 u0, u1;
  u0.x = f2bf(f0.x); u0.y = f2bf(f0.y); u0.z = f2bf(f0.z); u0.w = f2bf(f0.w);
  u1.x = f2bf(f1.x); u1.y = f2bf(f1.y); u1.z = f2bf(f1.z); u1.w = f2bf(f1.w);
  *(ushort4*)(out + e) = u0;
  *(ushort4*)(out + e + 4) = u1;
}

// ---------------------------------------------------------------------------
// bf16 GEMM core: C[M=4096, N=1024] = A[M,1024] @ W[N,1024]^T + bias
// R11: BK=64 (was 32) -> 16 K-iterations instead of 32, halving the
// per-iteration barrier+vmcnt-drain overhead that R6/R7/R10 proved is the
// structural cost (counted-vmcnt, 3-buf, and 2x occupancy were all null).
// Per wave-iter: 16 MFMA + 12 ds_read_b128. LDS (16+8)KB x 2buf = 48 KB ->
// 3 blocks/CU capacity (>= the ~2.7 measured resident; avoids the m132
// BK=128 occupancy trap). 128-byte rows use the 8-slot swizzle
// slot = cc ^ (row&7): bank = f(slot) only (row*128B = 0 mod 32 banks), so
// worst case 2 lanes/slot = free 2-way. Pre-swizzled global source + same
// XOR on ds_read (rule #21). T3 minimum schedule: STAGE(t+1) at top,
// compute t, __syncthreads() at bottom.
// MODE 0: bf16 out, permuted [b,h,s,64], value scaled by `scale`
// MODE 1: bf16 out, transposed [b,h,64,s]  (for V)
// MODE 2: f32 out, plain row-major [M,N]
// ---------------------------------------------------------------------------
template <int MODE>
__device__ __forceinline__ void gemm128x64(
    const u16* __restrict__ A, const u16* __restrict__ W,
    const float* __restrict__ bias, void* __restrict__ out,
    float scale, u16* As, u16* Bs)
{
  const int tid = threadIdx.x;
  const int wid = tid >> 6, lane = tid & 63;
  const int g = lane >> 4, l16 = lane & 15;
  const int wr = wid >> 1, wc = wid & 1;
  const int brow = blockIdx.x * 128, bcol = blockIdx.y * 64;

  f32x4 acc[4][2] = {};
  const u16* Ab = A + (size_t)brow * 1024;
  const u16* Wb = W + (size_t)bcol * 1024;

  // stage K-tile kt2 (64 wide) into buffer `buf`: A 1024 chunks (4/thread),
  // B 512 chunks (2/thread); 16B chunks, linear LDS dest, pre-swizzled source.
  auto STAGE = [&](int buf, int kt2) {
    const int k0 = kt2 * 64;
    u16* Ad = As + buf * 8192;
    u16* Bd = Bs + buf * 4096;
#pragma unroll
    for (int i = 0; i < 4; ++i) {
      const int chunk = i * 256 + tid;
      const int row = chunk >> 3, cc = chunk & 7;
      const int sc = (cc ^ (row & 7)) * 8;
      async_copy16(Ab + (size_t)row * 1024 + k0 + sc, Ad + (i * 256 + wid * 64) * 8);
    }
#pragma unroll
    for (int j = 0; j < 2; ++j) {
      const int chunk = j * 256 + tid;
      const int row = chunk >> 3, cc = chunk & 7;
      const int sc = (cc ^ (row & 7)) * 8;
      async_copy16(Wb + (size_t)row * 1024 + k0 + sc, Bd + (j * 256 + wid * 64) * 8);
    }
  };

  STAGE(0, 0);
  __syncthreads();

  for (int kt = 0; kt < 16; ++kt) {
    if (kt < 15) STAGE((kt + 1) & 1, kt + 1);   // prefetch next tile (async)

    const u16* Ac = As + (kt & 1) * 8192;
    const u16* Bc = Bs + (kt & 1) * 4096;

    // global k-chunk gc = kk*4+g lives at LDS slot gc ^ (row&7)
    bf16x8 a[4][2], b[2][2];
#pragma unroll
    for (int m = 0; m < 4; ++m) {
      const int row = wr * 64 + m * 16 + l16;
#pragma unroll
      for (int kk = 0; kk < 2; ++kk)
        a[m][kk] = ldb8(Ac + row * 64 + (((kk * 4 + g) ^ (row & 7)) * 8));
    }
#pragma unroll
    for (int n = 0; n < 2; ++n) {
      const int row = wc * 32 + n * 16 + l16;
#pragma unroll
      for (int kk = 0; kk < 2; ++kk)
        b[n][kk] = ldb8(Bc + row * 64 + (((kk * 4 + g) ^ (row & 7)) * 8));
    }
#pragma unroll
    for (int m = 0; m < 4; ++m)
#pragma unroll
      for (int n = 0; n < 2; ++n) {
        acc[m][n] = __builtin_amdgcn_mfma_f32_16x16x32_bf16(a[m][0], b[n][0], acc[m][n], 0, 0, 0);
        acc[m][n] = __builtin_amdgcn_mfma_f32_16x16x32_bf16(a[m][1], b[n][1], acc[m][n], 0, 0, 0);
      }

    __syncthreads();  // drains vmcnt (stage kt+1, issued a full compute ago) + lgkm
  }

  // epilogue
#pragma unroll
  for (int m = 0; m < 4; ++m) {
    const int mg = brow + wr * 64 + m * 16 + g * 4;  // + j
#pragma unroll
    for (int n = 0; n < 2; ++n) {
      const int cg = bcol + wc * 32 + n * 16 + l16;
      const float bb = bias[cg];
      if constexpr (MODE == 0) {
        const int h = cg >> 6, d = cg & 63;
#pragma unroll
        for (int j = 0; j < 4; ++j) {
          const int row = mg + j;
          const int bb_ = row >> 11, s = row & 2047;
          ((u16*)out)[(((size_t)(bb_ * 16 + h) * 2048 + s) << 6) + d] =
              f2bf((acc[m][n][j] + bb) * scale);
        }
      } else if constexpr (MODE == 1) {
        const int h = cg >> 6, d = cg & 63;
        const int bb_ = mg >> 11, s0 = mg & 2047;
        ushort4 pk;
        pk.x = f2bf(acc[m][n][0] + bb);
        pk.y = f2bf(acc[m][n][1] + bb);
        pk.z = f2bf(acc[m][n][2] + bb);
        pk.w = f2bf(acc[m][n][3] + bb);
        *(ushort4*)((u16*)out + ((size_t)(bb_ * 16 + h) * 64 + d) * 2048 + s0) = pk;
      } else {
#pragma unroll
        for (int j = 0; j < 4; ++j) {
          const int row = mg + j;
          ((float*)out)[(size_t)row * 1024 + cg] = acc[m][n][j] + bb;
        }
      }
    }
  }
}

__global__ __launch_bounds__(256) void qkv_gemm_kernel(
    const u16* __restrict__ xq, const u16* __restrict__ xk, const u16* __restrict__ xv,
    const u16* __restrict__ wq, const u16* __restrict__ wk, const u16* __restrict__ wv,
    const float* __restrict__ bq, const float* __restrict__ bk, const float* __restrict__ bv,
    u16* __restrict__ oq, u16* __restrict__ ok, u16* __restrict__ ov)
{
  __shared__ u16 As[2][8192];
  __shared__ u16 Bs[2][4096];
  const int z = blockIdx.z;
  // Q pre-scaled by 1/sqrt(64) * log2(e): attention then uses p = exp2(s) directly.
  if (z == 0)      gemm128x64<0>(xq, wq, bq, oq, 0.125f * LOG2E, &As[0][0], &Bs[0][0]);
  else if (z == 1) gemm128x64<0>(xk, wk, bk, ok, 1.0f, &As[0][0], &Bs[0][0]);    // K
  else             gemm128x64<1>(xv, wv, bv, ov, 1.0f, &As[0][0], &Bs[0][0]);    // V transposed
}

__global__ __launch_bounds__(256) void out_gemm_kernel(
    const u16* __restrict__ a, const u16* __restrict__ w,
    const float* __restrict__ bias, float* __restrict__ o)
{
  __shared__ u16 As[2][8192];
  __shared__ u16 Bs[2][4096];
  gemm128x64<2>(a, w, bias, o, 1.0f, &As[0][0], &Bs[0][0]);
}

// ---------------------------------------------------------------------------
// Kernel 3: flash attention (R10 structure, unchanged): 8 waves (512 threads),
// KV-sequence split -- waves 0-3 even KV tiles, waves 4-7 odd tiles; fixed-max
// softmax makes the final combine exact (O and l just add). 32x32x16 MFMA
// swapped QK^T, in-register P via cvt_pk + permlane32_swap, row-sum on the
// matrix pipe (ones-MFMA). Grid 512 (XCD-chunked).
// ---------------------------------------------------------------------------
__global__ __launch_bounds__(512) void attn_kernel(
    const u16* __restrict__ qp, const u16* __restrict__ kp,
    const u16* __restrict__ vt, u16* __restrict__ ao)
{
  __shared__ u16 Kbuf[4][4096];      // [4][2 d-half][64 k][32] bf16, 8 KB each
  __shared__ u16 Vbuf[4][4096];      // [4][2 s-half][64 d][32] bf16, 8 KB each

  const int tid = threadIdx.x;
  const int wid = tid >> 6, lane = tid & 63;
  const int u = lane >> 5, l32 = lane & 31;
  const int wsub = wid & 3, g2 = wid >> 2;   // q-tile owner / KV parity group

  // XCD-chunked remap: 512 blocks, 8 XCDs -> each XCD owns 4 whole heads.
  int bid = (int)blockIdx.x;
  bid = (bid & 7) * 64 + (bid >> 3);
  const int bh = bid >> 4;                 // b*16 + h
  const int q0 = (bid & 15) * 128 + wsub * 32;

  const u16* Q = qp + ((size_t)bh * 2048 + q0) * 64;
  const u16* K = kp + (size_t)bh * 2048 * 64;
  const u16* V = vt + (size_t)bh * 64 * 2048;

  // Q as B-fragments: col = q = l32, k-window = u*8 within each 16-d step
  bf16x8 aq[4];
#pragma unroll
  for (int st = 0; st < 4; ++st)
    aq[st] = ldb8(Q + l32 * 64 + st * 16 + u * 8);

  f32x16 outa[2] = {};   // C[q_row][d=nb*32+l32] (partial: this wave's tiles)
  f32x16 outsum = {};    // C[q_row][*] = partial row-sum of P (denominator)
  f32x16 zf16 = {};

  const __bf16 one_bf = (__bf16)1.0f;
  bf16x8 ones = {one_bf, one_bf, one_bf, one_bf, one_bf, one_bf, one_bf, one_bf};

  // stage ONE tile (512 threads, 1 K-load + 1 V-load per thread).
  auto STAGE1 = [&](int buf, int kb) {
    const int half = tid >> 8, row = (tid & 255) >> 2, slot = tid & 3;
    const int sc = (slot ^ ((row >> 1) & 3)) * 8;
    async_copy16(K + (size_t)(kb + row) * 64 + half * 32 + sc, &Kbuf[buf][wid * 512]);
    async_copy16(V + (size_t)row * 2048 + kb + half * 32 + sc, &Vbuf[buf][wid * 512]);
  };

  STAGE1(0, 0);      // tile 0
  STAGE1(1, 64);     // tile 1

  for (int T = 0; T < 16; ++T) {
    __syncthreads();
    if (T < 15) {
      STAGE1((2 * T + 2) & 3, (2 * T + 2) * 64);
      STAGE1((2 * T + 3) & 3, (2 * T + 3) * 64);
    }

    const int kt = 2 * T + g2;   // group 0: even tiles, group 1: odd tiles
    const u16* Kb = Kbuf[kt & 3];
    const u16* Vb = Vbuf[kt & 3];

    // Swapped QK^T: s[half] = K[half*32..+31][:] . Q -> P[k][q=l32]
    f32x16 s[2];
    __builtin_amdgcn_s_setprio(1);
#pragma unroll
    for (int half = 0; half < 2; ++half) {
      const int krow = half * 32 + l32;
#pragma unroll
      for (int st = 0; st < 4; ++st) {
        const bf16x8 kf = ldb8(Kb + (st >> 1) * 2048 + krow * 32 +
                               ((((st & 1) * 2 + u) ^ ((krow >> 1) & 3)) * 8));
        s[half] = __builtin_amdgcn_mfma_f32_32x32x16_bf16(
            kf, aq[st], (st == 0) ? zf16 : s[half], 0, 0, 0);
      }
    }
    __builtin_amdgcn_s_setprio(0);

    // p = exp2(s); pack adjacent-k pairs to one bf16x2 word per cvt_pk inst
    u32 Wd[2][8];
#pragma unroll
    for (int half = 0; half < 2; ++half) {
#pragma unroll
      for (int p = 0; p < 8; ++p) {
        const float p0 = __builtin_amdgcn_exp2f(s[half][2 * p]);
        const float p1 = __builtin_amdgcn_exp2f(s[half][2 * p + 1]);
        u32 w;
        asm("v_cvt_pk_bf16_f32 %0, %1, %2" : "=v"(w) : "v"(p0), "v"(p1));
        Wd[half][p] = w;
      }
    }

    // PV: 4 k-steps of 16. A-frag assembled by two half-wave swaps.
#pragma unroll
    for (int t = 0; t < 4; ++t) {
      u32 c0 = Wd[t >> 1][(t & 1) * 4 + 0];
      u32 c1 = Wd[t >> 1][(t & 1) * 4 + 1];
      u32 c2 = Wd[t >> 1][(t & 1) * 4 + 2];
      u32 c3 = Wd[t >> 1][(t & 1) * 4 + 3];
      asm volatile("v_permlane32_swap_b32 %0, %1" : "+v"(c0), "+v"(c2));
      asm volatile("v_permlane32_swap_b32 %0, %1" : "+v"(c1), "+v"(c3));
      u32x4 wv = {c0, c1, c2, c3};
      const bf16x8 paf = __builtin_bit_cast(bf16x8, wv);
      __builtin_amdgcn_s_setprio(1);
      outsum = __builtin_amdgcn_mfma_f32_32x32x16_bf16(paf, ones, outsum, 0, 0, 0);
#pragma unroll
      for (int nb = 0; nb < 2; ++nb) {
        const int dv = nb * 32 + l32;
        const bf16x8 vf = ldb8(Vb + (t >> 1) * 2048 + dv * 32 +
                               ((((t & 1) * 2 + u) ^ ((dv >> 1) & 3)) * 8));
        outa[nb] = __builtin_amdgcn_mfma_f32_32x32x16_bf16(paf, vf, outa[nb], 0, 0, 0);
      }
      __builtin_amdgcn_s_setprio(0);
    }
  }

  // ---- exact combine: waves 4-7 publish partials, waves 0-3 add + store ----
  __syncthreads();   // all compute reads done; K/V buffers reusable
  float* exA = (float*)&Kbuf[0][0];   // 4 waves x 8 KB  = 32 KB (outa)
  float* exS = (float*)&Vbuf[0][0];   // 4 waves x 4 KB  = 16 KB (outsum)
  if (wid >= 4) {
    const int ba = (wid - 4) * 2048 + lane * 32;
#pragma unroll
    for (int nb = 0; nb < 2; ++nb)
#pragma unroll
      for (int r = 0; r < 16; ++r) exA[ba + nb * 16 + r] = outa[nb][r];
    const int bs = (wid - 4) * 1024 + lane * 16;
#pragma unroll
    for (int r = 0; r < 16; ++r) exS[bs + r] = outsum[r];
  }
  __syncthreads();
  if (wid < 4) {
    const int ba = wid * 2048 + lane * 32;
#pragma unroll
    for (int nb = 0; nb < 2; ++nb)
#pragma unroll
      for (int r = 0; r < 16; ++r) outa[nb][r] += exA[ba + nb * 16 + r];
    const int bs = wid * 1024 + lane * 16;
#pragma unroll
    for (int r = 0; r < 16; ++r) outsum[r] += exS[bs + r];

    const int b = bh >> 4, h = bh & 15;
#pragma unroll
    for (int r = 0; r < 16; ++r) {
      const int qr = (r & 3) + 8 * (r >> 2) + 4 * u;
      const float inv = 1.0f / outsum[r];
      const int srow = q0 + qr;
#pragma unroll
      for (int nb = 0; nb < 2; ++nb) {
        ao[((size_t)b * 2048 + srow) * 1024 + h * 64 + nb * 32 + l32] =
            __builtin_bit_cast(u16, (__bf16)(outa[nb][r] * inv));
      }
    }
  }
}

// ---------------------------------------------------------------------------
extern "C" void kernel_launch(void* const* d_in, const int* in_sizes, int n_in,
                              void* d_out, int out_size, void* d_ws, size_t ws_size,
                              hipStream_t stream) {
  const float* q  = (const float*)d_in[0];
  const float* k  = (const float*)d_in[1];
  const float* v  = (const float*)d_in[2];
  const float* Wq = (const float*)d_in[3];
  const float* bq = (const float*)d_in[4];
  const float* Wk = (const float*)d_in[5];
  const float* bk = (const float*)d_in[6];
  const float* Wv = (const float*)d_in[7];
  const float* bv = (const float*)d_in[8];
  const float* Wo = (const float*)d_in[9];
  const float* bo = (const float*)d_in[10];

  u16* ws = (u16*)d_ws;
  u16* xq   = ws;                  // query bf16   (4M)
  u16* xk   = ws + 4194304;        // key bf16     (4M)
  u16* xv   = ws + 8388608;        // value bf16   (4M)
  u16* wqb  = ws + 12582912;       // Wq bf16      (1M)
  u16* wkb  = ws + 13631488;
  u16* wvb  = ws + 14680064;
  u16* wob  = ws + 15728640;
  u16* qperm = ws + 16777216;      // Q  [b,h,s,64]  (4M)
  u16* kperm = ws + 20971520;      // K  [b,h,s,64]  (4M)
  u16* vtp   = ws + 25165824;      // V^T[b,h,64,s]  (4M)
  u16* aout  = ws + 29360128;      // attn out [b,s,1024] (4M)
  // total: 64 MB of workspace

  convert_kernel<<<8192, 256, 0, stream>>>(q, k, v, Wq, Wk, Wv, Wo, ws);
  qkv_gemm_kernel<<<dim3(32, 16, 3), 256, 0, stream>>>(xq, xk, xv, wqb, wkb, wvb,
                                                       bq, bk, bv, qperm, kperm, vtp);
  attn_kernel<<<512, 512, 0, stream>>>(qperm, kperm, vtp, aout);
  out_gemm_kernel<<<dim3(32, 16), 256, 0, stream>>>(aout, wob, bo, (float*)d_out);
}